// Round 19
// baseline (111.505 us; speedup 1.0000x reference)
//
#include <hip/hip_runtime.h>

#define F_DIMC 64
#define K_DIMC 16
#define NGRAPH 64
#define NXCD 8
#define SX_WAVES 8
#define SX_SPLIT 8
#define NB_SEL 400                         // N/256
#define NB_CHUNK 256                       // histogram/scatter chunks
#define NB_ZERO 64
#define CHUNK_I4 800                       // int4s per chunk (hist)
#define CHUNK_E 3200                       // edges per chunk (scatter)
#define ADJ_BLOCKS 256                     // 4/graph
#define ADJ_OFF (NGRAPH * K_DIMC * F_DIMC)
#define LOSS_OFF (ADJ_OFF + NGRAPH * K_DIMC * K_DIMC)
#define ZERO_BYTES 394240

typedef __attribute__((ext_vector_type(8))) short s16x8;
typedef __attribute__((ext_vector_type(4))) float f32x4;

// ---------------- workspace layout (bytes) ----------------
// zeroed each call (zero-role blocks of k_sel_hist): [0, 394240)
//   [0,256) den | [256,512) donecnt | [512,768) lossws | [768,1024) pad
//   [1024,66560) dense_raw | [66560,132096) ssbuf | [132096,394240) sxbuf
// not zeroed:
//   [394240,394496) offsets | [394496,394752) gtot
//   [394752,460288) blockhist | [460288,525824) chunkbase
//   [525824,7079424)  sel  (float[N*16])
//   [7079424,33293824)  Abuf (bf16[E*16], edge-major, counting-sorted by graph)
//   [33293824,59508224) Bbuf (bf16[E*16])

__device__ inline unsigned short f2bf(float f) {
    unsigned u = __builtin_bit_cast(unsigned, f);
    u += 0x7fffu + ((u >> 16) & 1u);       // RNE
    return (unsigned short)(u >> 16);
}

// ---- fused: selection [0,NB_SEL) || per-chunk histogram || ws zeroing ----
__global__ __launch_bounds__(256) void k_sel_hist(const float* __restrict__ node_attr,
                                                  const float* __restrict__ W,
                                                  const float* __restrict__ bias,
                                                  const int* __restrict__ row,
                                                  float* __restrict__ sel,
                                                  int* __restrict__ blockhist,
                                                  float4* __restrict__ zdst,
                                                  int N, int perG) {
    int t = threadIdx.x;
    if (blockIdx.x < NB_SEL) {
        __shared__ float sW[K_DIMC][F_DIMC];
        __shared__ float sb[K_DIMC];
        for (int idx = t; idx < F_DIMC * K_DIMC; idx += 256) {
            int f = idx / K_DIMC, k = idx % K_DIMC;
            sW[k][f] = W[idx];
        }
        if (t < K_DIMC) sb[t] = bias[t];
        __syncthreads();
        int n = blockIdx.x * 256 + t;
        if (n >= N) return;

        const float4* xr = (const float4*)(node_attr + (size_t)n * F_DIMC);
        float4 x[F_DIMC / 4];
#pragma unroll
        for (int f4 = 0; f4 < F_DIMC / 4; ++f4) x[f4] = xr[f4];

        float logits[K_DIMC];
#pragma unroll
        for (int k = 0; k < K_DIMC; ++k) {
            const float4* wk = (const float4*)&sW[k][0];
            float acc = sb[k];
#pragma unroll
            for (int f4 = 0; f4 < F_DIMC / 4; ++f4) {
                float4 w = wk[f4];
                acc += x[f4].x * w.x + x[f4].y * w.y + x[f4].z * w.z + x[f4].w * w.w;
            }
            logits[k] = acc;
        }
        float m = logits[0];
#pragma unroll
        for (int k = 1; k < K_DIMC; ++k) m = fmaxf(m, logits[k]);
        float sum = 0.f;
#pragma unroll
        for (int k = 0; k < K_DIMC; ++k) {
            float e = __expf(logits[k] - m);
            logits[k] = e;
            sum += e;
        }
        float inv = 1.f / sum;
        float4* sd = (float4*)(sel + (size_t)n * K_DIMC);
#pragma unroll
        for (int k4 = 0; k4 < K_DIMC / 4; ++k4) {
            float4 v;
            v.x = logits[4 * k4 + 0] * inv;
            v.y = logits[4 * k4 + 1] * inv;
            v.z = logits[4 * k4 + 2] * inv;
            v.w = logits[4 * k4 + 3] * inv;
            sd[k4] = v;
        }
    } else if (blockIdx.x < NB_SEL + NB_CHUNK) {
        __shared__ int lh[NGRAPH];
        int h = blockIdx.x - NB_SEL;                 // 0..255, static chunk
        if (t < NGRAPH) lh[t] = 0;
        __syncthreads();
        for (int i = t; i < CHUNK_I4; i += 256) {
            int4 r4 = ((const int4*)row)[h * CHUNK_I4 + i];
            atomicAdd(&lh[r4.x / perG], 1);
            atomicAdd(&lh[r4.y / perG], 1);
            atomicAdd(&lh[r4.z / perG], 1);
            atomicAdd(&lh[r4.w / perG], 1);
        }
        __syncthreads();
        if (t < NGRAPH) blockhist[h * NGRAPH + t] = lh[t];
    } else {
        int z = blockIdx.x - NB_SEL - NB_CHUNK;
        for (int i = z * 256 + t; i < ZERO_BYTES / 16; i += NB_ZERO * 256)
            zdst[i] = make_float4(0.f, 0.f, 0.f, 0.f);
    }
}

// ---- per-graph exclusive scan over 256 chunks: chunkbase[b][g], gtot[g] ----
__global__ __launch_bounds__(256) void k_chunkscan(const int* __restrict__ blockhist,
                                                   int* __restrict__ chunkbase,
                                                   int* __restrict__ gtot) {
    int g = blockIdx.x;
    int t = threadIdx.x;                 // 0..255 = chunk index
    int lane = t & 63;
    int wid = t >> 6;
    int v = blockhist[t * NGRAPH + g];
    int s = v;
#pragma unroll
    for (int d = 1; d < 64; d <<= 1) {
        int o = __shfl_up(s, d);
        if (lane >= d) s += o;
    }
    __shared__ int wsum[4];
    if (lane == 63) wsum[wid] = s;
    __syncthreads();
    int pre = 0;
#pragma unroll
    for (int w = 0; w < 4; ++w) pre += (w < wid) ? wsum[w] : 0;
    int incl = s + pre;
    chunkbase[t * NGRAPH + g] = incl - v;
    if (t == 255) gtot[g] = incl;
}

// ---- scatter-build: gather sel rows per edge (dense per-lane 16B gathers),
// convert to bf16, write edge-major A/B tables counting-sorted by graph.
// Also accumulates den[g] = sum_e ||sel[row_e]||^2 via LDS (round-4 pattern).
__global__ __launch_bounds__(256) void k_scatter(const int* __restrict__ row,
                                                 const int* __restrict__ col,
                                                 const int* __restrict__ gtot,
                                                 const int* __restrict__ chunkbase,
                                                 int* __restrict__ offsets,
                                                 const float* __restrict__ sel,
                                                 unsigned short* __restrict__ Abuf,
                                                 unsigned short* __restrict__ Bbuf,
                                                 float* __restrict__ den,
                                                 int perG) {
    __shared__ int base_[NGRAPH];
    __shared__ int lcnt[NGRAPH];
    __shared__ float lden[NGRAPH];
    int t = threadIdx.x;
    int h = blockIdx.x;                  // 0..255, same chunk as hist
    if (t < 64) {
        int v = gtot[t];
        int s = v;
#pragma unroll
        for (int d = 1; d < 64; d <<= 1) {
            int o = __shfl_up(s, d);
            if (t >= d) s += o;
        }
        int offs = s - v;                // exclusive scan = graph base
        base_[t] = offs + chunkbase[h * NGRAPH + t];
        lcnt[t] = 0;
        lden[t] = 0.f;
        if (h == 0) offsets[t] = offs;
    }
    __syncthreads();
    for (int i = t; i < CHUNK_E; i += 256) {
        int e = h * CHUNK_E + i;
        int r = row[e];
        int c = col[e];
        int g = r / perG;
        int lpos = atomicAdd(&lcnt[g], 1);
        size_t dest = (size_t)(base_[g] + lpos) * K_DIMC;
        // gather sel[r] (A-row) + q accumulation
        const float4* sr = (const float4*)(sel + (size_t)r * K_DIMC);
        float4 r0 = sr[0], r1 = sr[1], r2 = sr[2], r3 = sr[3];
        float q = r0.x * r0.x + r0.y * r0.y + r0.z * r0.z + r0.w * r0.w
                + r1.x * r1.x + r1.y * r1.y + r1.z * r1.z + r1.w * r1.w
                + r2.x * r2.x + r2.y * r2.y + r2.z * r2.z + r2.w * r2.w
                + r3.x * r3.x + r3.y * r3.y + r3.z * r3.z + r3.w * r3.w;
        atomicAdd(&lden[g], q);
        s16x8 alo, ahi;
        alo[0] = f2bf(r0.x); alo[1] = f2bf(r0.y); alo[2] = f2bf(r0.z); alo[3] = f2bf(r0.w);
        alo[4] = f2bf(r1.x); alo[5] = f2bf(r1.y); alo[6] = f2bf(r1.z); alo[7] = f2bf(r1.w);
        ahi[0] = f2bf(r2.x); ahi[1] = f2bf(r2.y); ahi[2] = f2bf(r2.z); ahi[3] = f2bf(r2.w);
        ahi[4] = f2bf(r3.x); ahi[5] = f2bf(r3.y); ahi[6] = f2bf(r3.z); ahi[7] = f2bf(r3.w);
        *(s16x8*)(Abuf + dest) = alo;
        *(s16x8*)(Abuf + dest + 8) = ahi;
        // gather sel[c] (B-row)
        const float4* sc = (const float4*)(sel + (size_t)c * K_DIMC);
        float4 c0 = sc[0], c1 = sc[1], c2 = sc[2], c3 = sc[3];
        s16x8 blo, bhi;
        blo[0] = f2bf(c0.x); blo[1] = f2bf(c0.y); blo[2] = f2bf(c0.z); blo[3] = f2bf(c0.w);
        blo[4] = f2bf(c1.x); blo[5] = f2bf(c1.y); blo[6] = f2bf(c1.z); blo[7] = f2bf(c1.w);
        bhi[0] = f2bf(c2.x); bhi[1] = f2bf(c2.y); bhi[2] = f2bf(c2.z); bhi[3] = f2bf(c2.w);
        bhi[4] = f2bf(c3.x); bhi[5] = f2bf(c3.y); bhi[6] = f2bf(c3.z); bhi[7] = f2bf(c3.w);
        *(s16x8*)(Bbuf + dest) = blo;
        *(s16x8*)(Bbuf + dest + 8) = bhi;
    }
    __syncthreads();
    if (t < 64) {
        if (lcnt[t]) atomicAdd(den + t, lden[t]);
    }
}

// ---- adj via MFMA: dense_raw[g] = Amat_g^T (16 x cnt) * Bmat_g (cnt x 16).
// 256 blocks (4/graph, XCD-grouped), 4 waves each; per 32-edge K-chunk:
// stage A/B tiles (2 coalesced b128 loads + 2 ds_write_b128), read frags as
// 8+8 ds_read_u16 (lane l: elem [k=8*(l>>4)+d][m=l&15] -- k-contiguous-8
// layout, m92/m97 evidence), 1 x mfma_f32_16x16x32_bf16. ~19 instr/32 edges
// vs 64 for the broadcast-gather formulation (rounds 12-18: 39-45us wall).
__global__ __launch_bounds__(256) void k_adj(const int* __restrict__ offsets,
                                             const int* __restrict__ gtot,
                                             const unsigned short* __restrict__ Abuf,
                                             const unsigned short* __restrict__ Bbuf,
                                             float* __restrict__ dense_raw) {
    __shared__ unsigned short At[4][512];    // per-wave 32 edges x 16 (1KB)
    __shared__ unsigned short Bt[4][512];
    __shared__ float lacc[4][256];
    int b = blockIdx.x;
    int xcd = b & (NXCD - 1);
    int idx = b >> 3;                        // 0..31
    int g = xcd * (NGRAPH / NXCD) + (idx >> 2);
    int split = idx & 3;
    int t = threadIdx.x;
    int wid = t >> 6;
    int lane = t & 63;
    int m = lane & 15;
    int grp = lane >> 4;

    int start = offsets[g];
    int cnt = gtot[g];
    int wslot = split * 4 + wid;             // 0..15
    f32x4 acc = {0.f, 0.f, 0.f, 0.f};
    int nch = (cnt + 31) >> 5;
    for (int ch = wslot; ch < nch; ch += 16) {
        int e0 = ch << 5;
        // stage: lane covers elems [lane*8, lane*8+8) of the 512-elem tile
        // = edge e0 + (lane>>1), half (lane&1)
        if (e0 + (lane >> 1) < cnt) {
            const s16x8* srcA = (const s16x8*)(Abuf + (size_t)(start + e0) * K_DIMC) + lane;
            const s16x8* srcB = (const s16x8*)(Bbuf + (size_t)(start + e0) * K_DIMC) + lane;
            ((s16x8*)At[wid])[lane] = *srcA;
            ((s16x8*)Bt[wid])[lane] = *srcB;
        } else {
            s16x8 z = {0, 0, 0, 0, 0, 0, 0, 0};
            ((s16x8*)At[wid])[lane] = z;
            ((s16x8*)Bt[wid])[lane] = z;
        }
        // per-wave LDS; compiler inserts lgkmcnt before dependent reads
        s16x8 av, bv;
#pragma unroll
        for (int d = 0; d < 8; ++d) {
            int off = (8 * grp + d) * K_DIMC + m;
            av[d] = (short)At[wid][off];
            bv[d] = (short)Bt[wid][off];
        }
        acc = __builtin_amdgcn_mfma_f32_16x16x32_bf16(av, bv, acc, 0, 0, 0);
    }
    // C layout (m89): col = lane&15, row = (lane>>4)*4 + reg
#pragma unroll
    for (int d = 0; d < 4; ++d) {
        lacc[wid][(4 * grp + d) * K_DIMC + m] = acc[d];
    }
    __syncthreads();
    float s = lacc[0][t] + lacc[1][t] + lacc[2][t] + lacc[3][t];
    atomicAdd(dense_raw + g * 256 + t, s);   // 4 contenders/cell
}

// ---- SX/SS: grid (SX_SPLIT, NGRAPH), 8 waves ----
__global__ __launch_bounds__(512) void k_sx(const float* __restrict__ sel,
                                            const float* __restrict__ x,
                                            float* __restrict__ ssbuf,
                                            float* __restrict__ sxbuf, int perG) {
    int g = blockIdx.y;
    int wid = threadIdx.x >> 6;
    int wslot = blockIdx.x * SX_WAVES + wid;     // 0..63
    int lane = threadIdx.x & 63;
    int k = lane >> 2;
    int sub = lane & 3;
    int f0 = sub * 16;
    int j0 = sub * 4;
    float accss[4] = {0.f, 0.f, 0.f, 0.f};
    float accsx[16];
#pragma unroll
    for (int j = 0; j < 16; ++j) accsx[j] = 0.f;
    size_t base = (size_t)g * perG;
    int stride = SX_SPLIT * SX_WAVES;            // 64
#pragma unroll 2
    for (int nn = wslot; nn < perG; nn += stride) {
        size_t node = base + nn;
        float a = sel[node * K_DIMC + k];
        float4 s4 = *(const float4*)(sel + node * K_DIMC + j0);
        accss[0] += a * s4.x;
        accss[1] += a * s4.y;
        accss[2] += a * s4.z;
        accss[3] += a * s4.w;
        const float4* xv = (const float4*)(x + node * F_DIMC + f0);
#pragma unroll
        for (int j = 0; j < 4; ++j) {
            float4 v = xv[j];
            accsx[4 * j + 0] += a * v.x;
            accsx[4 * j + 1] += a * v.y;
            accsx[4 * j + 2] += a * v.z;
            accsx[4 * j + 3] += a * v.w;
        }
    }
    __shared__ float lsx[SX_WAVES][K_DIMC * F_DIMC];  // 32 KB
    __shared__ float lss[SX_WAVES][256];              // 8 KB
#pragma unroll
    for (int j4 = 0; j4 < 4; ++j4) {
        *(float4*)&lsx[wid][k * F_DIMC + f0 + 4 * j4] =
            make_float4(accsx[4 * j4], accsx[4 * j4 + 1], accsx[4 * j4 + 2], accsx[4 * j4 + 3]);
    }
    *(float4*)&lss[wid][k * K_DIMC + j0] = make_float4(accss[0], accss[1], accss[2], accss[3]);
    __syncthreads();
    for (int c = threadIdx.x; c < K_DIMC * F_DIMC; c += 512) {
        float s = 0.f;
#pragma unroll
        for (int w = 0; w < SX_WAVES; ++w) s += lsx[w][c];
        atomicAdd(sxbuf + (size_t)g * (K_DIMC * F_DIMC) + c, s);
    }
    if (threadIdx.x < 256) {
        int c = threadIdx.x;
        float s = 0.f;
#pragma unroll
        for (int w = 0; w < SX_WAVES; ++w) s += lss[w][c];
        atomicAdd(ssbuf + g * 256 + c, s);
    }
}

// ---- finalize: normalize adj, copy SX to out, losses via ws + last-block write ----
__global__ __launch_bounds__(256) void k_fin(const float* __restrict__ dense_raw,
                                             const float* __restrict__ ssbuf,
                                             const float* __restrict__ sxbuf,
                                             const float* __restrict__ den,
                                             float* __restrict__ lossws,
                                             int* __restrict__ donecnt,
                                             float* __restrict__ out) {
    int g = blockIdx.x;
    int c = threadIdx.x;
    int k = c >> 4, j = c & 15;
    int lane = threadIdx.x & 63;
    int wid = threadIdx.x >> 6;

    ((float4*)(out + (size_t)g * (K_DIMC * F_DIMC)))[c] =
        ((const float4*)(sxbuf + (size_t)g * (K_DIMC * F_DIMC)))[c];

    float a = dense_raw[g * 256 + c];
    float s = a;
    s += __shfl_xor(s, 1);
    s += __shfl_xor(s, 2);
    s += __shfl_xor(s, 4);
    s += __shfl_xor(s, 8);
    __shared__ float dvrow[K_DIMC];
    if (j == 0) dvrow[k] = sqrtf(s) + 1e-15f;
    __syncthreads();
    float v = a / (dvrow[k] * dvrow[j]);
    out[ADJ_OFF + g * 256 + c] = v;

    float ss = ssbuf[g * 256 + c];
    float tt = (k == j) ? v : 0.f;
    float n2 = ss * ss;
#pragma unroll
    for (int off = 32; off > 0; off >>= 1) {
        tt += __shfl_down(tt, off);
        n2 += __shfl_down(n2, off);
    }
    __shared__ float redt[4], redn[4];
    if (lane == 0) { redt[wid] = tt; redn[wid] = n2; }
    __syncthreads();
    float tr = redt[0] + redt[1] + redt[2] + redt[3];
    float nrm2 = redn[0] + redn[1] + redn[2] + redn[3];
    float invn = 1.f / sqrtf(nrm2);
    float d = ss * invn - ((k == j) ? 0.25f : 0.f);
    float o2 = d * d;
#pragma unroll
    for (int off = 32; off > 0; off >>= 1) o2 += __shfl_down(o2, off);
    __shared__ float redo[4];
    if (lane == 0) redo[wid] = o2;
    __syncthreads();
    if (threadIdx.x == 0) {
        float osum = redo[0] + redo[1] + redo[2] + redo[3];
        float og = sqrtf(osum);
        float mterm = -(tr / den[g]);
        atomicAdd(lossws + 0, mterm * (1.f / NGRAPH));
        atomicAdd(lossws + 1, og * (1.f / NGRAPH));
        __threadfence();
        int old = atomicAdd(donecnt, 1);
        if (old == NGRAPH - 1) {
            float l0 = atomicAdd(lossws + 0, 0.f);
            float l1 = atomicAdd(lossws + 1, 0.f);
            out[LOSS_OFF + 0] = l0;
            out[LOSS_OFF + 1] = l1;
        }
    }
}

extern "C" void kernel_launch(void* const* d_in, const int* in_sizes, int n_in,
                              void* d_out, int out_size, void* d_ws, size_t ws_size,
                              hipStream_t stream) {
    const float* node_attr = (const float*)d_in[0];
    const float* W = (const float*)d_in[1];
    const float* bias = (const float*)d_in[2];
    const int* edge_index = (const int*)d_in[3];
    int N = in_sizes[0] / F_DIMC;
    int E = in_sizes[3] / 2;
    int perG = N / NGRAPH;
    const int* row = edge_index;
    const int* col = edge_index + E;
    float* out = (float*)d_out;
    char* ws = (char*)d_ws;

    float* den = (float*)(ws + 0);
    int* donecnt = (int*)(ws + 256);
    float* lossws = (float*)(ws + 512);
    float* dense_raw = (float*)(ws + 1024);
    float* ssbuf = (float*)(ws + 66560);
    float* sxbuf = (float*)(ws + 132096);
    int* offsets = (int*)(ws + 394240);
    int* gtot = (int*)(ws + 394496);
    int* blockhist = (int*)(ws + 394752);
    int* chunkbase = (int*)(ws + 460288);
    float* sel = (float*)(ws + 525824);
    unsigned short* Abuf = (unsigned short*)(ws + 7079424);
    unsigned short* Bbuf = (unsigned short*)(ws + 33293824);

    k_sel_hist<<<NB_SEL + NB_CHUNK + NB_ZERO, 256, 0, stream>>>(node_attr, W, bias, row, sel,
                                                                blockhist, (float4*)ws, N, perG);
    k_chunkscan<<<NGRAPH, 256, 0, stream>>>(blockhist, chunkbase, gtot);
    k_scatter<<<NB_CHUNK, 256, 0, stream>>>(row, col, gtot, chunkbase, offsets,
                                            sel, Abuf, Bbuf, den, perG);
    k_adj<<<ADJ_BLOCKS, 256, 0, stream>>>(offsets, gtot, Abuf, Bbuf, dense_raw);
    k_sx<<<dim3(SX_SPLIT, NGRAPH), 512, 0, stream>>>(sel, node_attr, ssbuf, sxbuf, perG);
    k_fin<<<NGRAPH, 256, 0, stream>>>(dense_raw, ssbuf, sxbuf, den, lossws, donecnt, out);
}